// Round 3
// baseline (356.739 us; speedup 1.0000x reference)
//
#include <hip/hip_runtime.h>
#include <cmath>

#define HH 96
#define WW 96
#define NPIX (HH * WW)
#define COEF 5.0f
#define BIGV 1.0e9f
#define RPB 4            // rows per block in the fill kernel
#define F4PR (NPIX / 4)  // 2304 float4 per row (= 9 * 256)

// Kernel 1: per-pixel flat_ computation + init dmax slot.
__global__ void k_flat(const float* __restrict__ img,
                       const float* __restrict__ thre,
                       const float* __restrict__ add,
                       float* __restrict__ flat_out,   // ws[0..NPIX)
                       float* __restrict__ dmax_slot)  // ws[NPIX]
{
    int t = blockIdx.x * blockDim.x + threadIdx.x;
    if (t == 0) *dmax_slot = 0.0f;  // int bits of 0.0f are 0
    if (t >= NPIX) return;
    int i = t / WW, j = t % WW;
    float v  = img[t];
    float th = thre[t];
    bool high = (v >= th);

    // 5x5 local max over "low" pixels (img < thre); 0 if none in window
    float mx = -BIGV;
    for (int di = -2; di <= 2; ++di) {
        int ni = i + di;
        if (ni < 0 || ni >= HH) continue;
        for (int dj = -2; dj <= 2; ++dj) {
            int nj = j + dj;
            if (nj < 0 || nj >= WW) continue;
            int n = ni * WW + nj;
            float nv = img[n];
            if (nv < thre[n]) mx = fmaxf(mx, nv);
        }
    }
    float maxlim = (mx <= -BIGV * 0.5f) ? 0.0f : mx;

    // 3x3 local min over "high" pixels (img >= thre); 0 if none in window
    float mn = BIGV;
    for (int di = -1; di <= 1; ++di) {
        int ni = i + di;
        if (ni < 0 || ni >= HH) continue;
        for (int dj = -1; dj <= 1; ++dj) {
            int nj = j + dj;
            if (nj < 0 || nj >= WW) continue;
            int n = ni * WW + nj;
            float nv = img[n];
            if (nv >= thre[n]) mn = fminf(mn, nv);
        }
    }
    float minlim = (mn >= BIGV * 0.5f) ? 0.0f : mn;

    float img_high = high ? v : 0.0f;
    float img_low  = high ? 0.0f : v;
    float ih = (img_high - minlim) / (1.0f - minlim + 1e-11f);
    float il = img_low / (maxlim + 1e-11f);
    flat_out[t] = ih + il + (high ? add[t] : 0.0f);
}

// Kernel 2: max over all edges of |flat_[r] - flat_[c]|
__global__ void k_dmax(const float* __restrict__ flat_, float* dmax_slot)
{
    int t = blockIdx.x * blockDim.x + threadIdx.x;
    float d = 0.0f;
    if (t < NPIX) {
        int i = t / WW, j = t % WW;
        float fc = flat_[t];
        if (j + 1 < WW) d = fmaxf(d, fabsf(fc - flat_[t + 1]));
        if (i + 1 < HH) d = fmaxf(d, fabsf(fc - flat_[t + WW]));
    }
    for (int off = 32; off > 0; off >>= 1)
        d = fmaxf(d, __shfl_down(d, off, 64));
    if ((threadIdx.x & 63) == 0)
        atomicMax((int*)dmax_slot, __float_as_int(d));  // d >= 0: int-bit order ok
}

// Kernel 3: fused fill+scatter, 4 rows per block. Candidate (col,val) pairs
// computed by threads 0..15, one barrier BEFORE any stores (nothing to
// drain), then a pure streaming pass with branch-free cndmask injection.
// total.max() normalization cancels between weights and row_sum.
__global__ void __launch_bounds__(256) k_fill(const float* __restrict__ flat_,
                                              const float* __restrict__ dmax_slot,
                                              float4* __restrict__ out4)
{
    int b = blockIdx.x;          // 0..2303
    int tid = threadIdx.x;
    int r0 = b * RPB;
    __shared__ int   s_col[RPB][4];
    __shared__ float s_val[RPB][4];

    if (tid < RPB * 4) {
        int lr = tid >> 2, d = tid & 3;
        int r = r0 + lr;
        int i = r / WW, j = r % WW;
        const int off[4] = {-WW, WW, -1, 1};
        bool ok = (d == 0) ? (i > 0)
                : (d == 1) ? (i < HH - 1)
                : (d == 2) ? (j > 0)
                           : (j < WW - 1);
        float tot = 0.0f;
        int   col = -2;  // sentinel: never equals a valid column
        if (ok) {
            int n = r + off[d];
            float dd = fabsf(flat_[r] - flat_[n]);
            float inv_d = 1.0f / (*dmax_slot + 1e-11f);
            tot = expf(-COEF) + expf(-COEF * dd * inv_d);  // spatial dist == 1
            col = n;
        }
        s_col[lr][d] = col;
        s_val[lr][d] = tot;
    }
    __syncthreads();
    if (tid < RPB) {
        float rs = s_val[tid][0] + s_val[tid][1] + s_val[tid][2] + s_val[tid][3];
        float inv = 1.0f / rs;   // >= 2*exp(-5) > 0 always
        for (int d = 0; d < 4; ++d) s_val[tid][d] *= inv;
    }
    __syncthreads();

    float4* base = out4 + (size_t)b * (RPB * F4PR);
    #pragma unroll
    for (int lr = 0; lr < RPB; ++lr) {
        int   c0 = s_col[lr][0], c1 = s_col[lr][1], c2 = s_col[lr][2], c3 = s_col[lr][3];
        float w0 = s_val[lr][0], w1 = s_val[lr][1], w2 = s_val[lr][2], w3 = s_val[lr][3];
        #pragma unroll
        for (int kk = 0; kk < 9; ++kk) {          // 2304 = 9 * 256: row-aligned
            int c4 = tid + kk * 256;
            int cb = c4 * 4;
            float4 v;
            v.x = (c0 == cb    ) ? w0 : (c1 == cb    ) ? w1 : (c2 == cb    ) ? w2 : (c3 == cb    ) ? w3 : 0.0f;
            v.y = (c0 == cb + 1) ? w0 : (c1 == cb + 1) ? w1 : (c2 == cb + 1) ? w2 : (c3 == cb + 1) ? w3 : 0.0f;
            v.z = (c0 == cb + 2) ? w0 : (c1 == cb + 2) ? w1 : (c2 == cb + 2) ? w2 : (c3 == cb + 2) ? w3 : 0.0f;
            v.w = (c0 == cb + 3) ? w0 : (c1 == cb + 3) ? w1 : (c2 == cb + 3) ? w2 : (c3 == cb + 3) ? w3 : 0.0f;
            base[lr * F4PR + c4] = v;
        }
    }
}

extern "C" void kernel_launch(void* const* d_in, const int* in_sizes, int n_in,
                              void* d_out, int out_size, void* d_ws, size_t ws_size,
                              hipStream_t stream)
{
    const float* img  = (const float*)d_in[0];
    const float* thre = (const float*)d_in[1];
    const float* add  = (const float*)d_in[2];
    float* out = (float*)d_out;
    float* ws  = (float*)d_ws;

    float* flat_ = ws;           // NPIX floats
    float* dmax  = ws + NPIX;    // 1 float

    const int tpb = 256;
    const int pix_blocks = (NPIX + tpb - 1) / tpb;

    k_flat<<<pix_blocks, tpb, 0, stream>>>(img, thre, add, flat_, dmax);
    k_dmax<<<pix_blocks, tpb, 0, stream>>>(flat_, dmax);
    k_fill<<<NPIX / RPB, tpb, 0, stream>>>(flat_, dmax, (float4*)out);
}

// Round 4
// 344.706 us; speedup vs baseline: 1.0349x; 1.0349x over previous
//
#include <hip/hip_runtime.h>
#include <cmath>

#define HH 96
#define WW 96
#define NPIX (HH * WW)
#define COEF 5.0f
#define BIGV 1.0e9f

// Kernel 1: per-pixel flat_ computation + init dmax slot.
__global__ void k_flat(const float* __restrict__ img,
                       const float* __restrict__ thre,
                       const float* __restrict__ add,
                       float* __restrict__ flat_out,   // ws[0..NPIX)
                       float* __restrict__ dmax_slot)  // ws[NPIX]
{
    int t = blockIdx.x * blockDim.x + threadIdx.x;
    if (t == 0) *dmax_slot = 0.0f;  // int bits of 0.0f are 0
    if (t >= NPIX) return;
    int i = t / WW, j = t % WW;
    float v  = img[t];
    float th = thre[t];
    bool high = (v >= th);

    // 5x5 local max over "low" pixels (img < thre); 0 if none in window
    float mx = -BIGV;
    for (int di = -2; di <= 2; ++di) {
        int ni = i + di;
        if (ni < 0 || ni >= HH) continue;
        for (int dj = -2; dj <= 2; ++dj) {
            int nj = j + dj;
            if (nj < 0 || nj >= WW) continue;
            int n = ni * WW + nj;
            float nv = img[n];
            if (nv < thre[n]) mx = fmaxf(mx, nv);
        }
    }
    float maxlim = (mx <= -BIGV * 0.5f) ? 0.0f : mx;

    // 3x3 local min over "high" pixels (img >= thre); 0 if none in window
    float mn = BIGV;
    for (int di = -1; di <= 1; ++di) {
        int ni = i + di;
        if (ni < 0 || ni >= HH) continue;
        for (int dj = -1; dj <= 1; ++dj) {
            int nj = j + dj;
            if (nj < 0 || nj >= WW) continue;
            int n = ni * WW + nj;
            float nv = img[n];
            if (nv >= thre[n]) mn = fminf(mn, nv);
        }
    }
    float minlim = (mn >= BIGV * 0.5f) ? 0.0f : mn;

    float img_high = high ? v : 0.0f;
    float img_low  = high ? 0.0f : v;
    float ih = (img_high - minlim) / (1.0f - minlim + 1e-11f);
    float il = img_low / (maxlim + 1e-11f);
    flat_out[t] = ih + il + (high ? add[t] : 0.0f);
}

// Kernel 2: max over all edges of |flat_[r] - flat_[c]|
__global__ void k_dmax(const float* __restrict__ flat_, float* dmax_slot)
{
    int t = blockIdx.x * blockDim.x + threadIdx.x;
    float d = 0.0f;
    if (t < NPIX) {
        int i = t / WW, j = t % WW;
        float fc = flat_[t];
        if (j + 1 < WW) d = fmaxf(d, fabsf(fc - flat_[t + 1]));
        if (i + 1 < HH) d = fmaxf(d, fabsf(fc - flat_[t + WW]));
    }
    for (int off = 32; off > 0; off >>= 1)
        d = fmaxf(d, __shfl_down(d, off, 64));
    if ((threadIdx.x & 63) == 0)
        atomicMax((int*)dmax_slot, __float_as_int(d));  // d >= 0: int-bit order ok
}

// Kernel 3: zero-fill the whole NxN output (re-poisoned to 0xAA each call).
// Same shape as the rocclr fill that measures 6.1 TB/s.
__global__ void k_zero(float4* __restrict__ out, long n4)
{
    long t = (long)blockIdx.x * blockDim.x + threadIdx.x;
    if (t < n4) out[t] = make_float4(0.0f, 0.0f, 0.0f, 0.0f);
}

// Kernel 4: scatter nonzeros. out[i, nb] = total_e / row_sum_i.
// (The total.max() normalization cancels exactly between weights and row_sum.)
__global__ void k_scatter(const float* __restrict__ flat_,
                          const float* __restrict__ dmax_slot,
                          float* __restrict__ out)
{
    int t = blockIdx.x * blockDim.x + threadIdx.x;
    if (t >= NPIX) return;
    int i = t / WW, j = t % WW;
    float fc = flat_[t];
    float inv_d = 1.0f / (*dmax_slot + 1e-11f);
    const float es = expf(-COEF);  // spatial term: 4-neighbor distance is always 1

    int   nbr[4];
    float tot[4];
    int   cnt = 0;
    float row_sum = 0.0f;
    const int  off[4] = {-WW, WW, -1, 1};
    const bool ok[4]  = { i > 0, i < HH - 1, j > 0, j < WW - 1 };
    for (int k = 0; k < 4; ++k) {
        if (!ok[k]) continue;
        int n = t + off[k];
        float d = fabsf(fc - flat_[n]);
        float total = es + expf(-COEF * d * inv_d);
        nbr[cnt] = n;
        tot[cnt] = total;
        ++cnt;
        row_sum += total;
    }
    float inv_rs = 1.0f / row_sum;  // row_sum >= 2*exp(-5) > 0 always
    size_t base = (size_t)t * NPIX;
    for (int k = 0; k < cnt; ++k)
        out[base + nbr[k]] = tot[k] * inv_rs;
}

extern "C" void kernel_launch(void* const* d_in, const int* in_sizes, int n_in,
                              void* d_out, int out_size, void* d_ws, size_t ws_size,
                              hipStream_t stream)
{
    const float* img  = (const float*)d_in[0];
    const float* thre = (const float*)d_in[1];
    const float* add  = (const float*)d_in[2];
    float* out = (float*)d_out;
    float* ws  = (float*)d_ws;

    float* flat_ = ws;           // NPIX floats
    float* dmax  = ws + NPIX;    // 1 float

    const int tpb = 256;
    const int pix_blocks = (NPIX + tpb - 1) / tpb;

    k_flat<<<pix_blocks, tpb, 0, stream>>>(img, thre, add, flat_, dmax);
    k_dmax<<<pix_blocks, tpb, 0, stream>>>(flat_, dmax);

    long n4 = (long)out_size / 4;  // out_size = NPIX*NPIX, divisible by 4
    int zero_blocks = (int)((n4 + tpb - 1) / tpb);
    k_zero<<<zero_blocks, tpb, 0, stream>>>((float4*)out, n4);

    k_scatter<<<pix_blocks, tpb, 0, stream>>>(flat_, dmax, out);
}